// Round 1
// baseline (275.267 us; speedup 1.0000x reference)
//
#include <hip/hip_runtime.h>
#include <math.h>

typedef unsigned short u16;
typedef unsigned int u32;
typedef __attribute__((ext_vector_type(8))) short short8;
typedef __attribute__((ext_vector_type(4))) short short4v;
typedef __attribute__((ext_vector_type(4))) float floatx4;

#define HN 16
#define KVN 4
#define HDN 64
#define BN_ 2
#define LN 2048
#define DN 1024

__device__ __forceinline__ u16 f2bf(float f) {
    u32 u = __float_as_uint(f);
    u32 r = (u + 0x7fffu + ((u >> 16) & 1u)) >> 16;
    return (u16)r;
}

// ---------------- cast x -> bf16 ----------------
__global__ __launch_bounds__(256) void cast_x_kernel(const float* __restrict__ x,
                                                     u16* __restrict__ xb, int n4) {
    int i = blockIdx.x * 256 + threadIdx.x;
    if (i < n4) {
        floatx4 v = ((const floatx4*)x)[i];
        short4v o;
        o[0] = (short)f2bf(v[0]);
        o[1] = (short)f2bf(v[1]);
        o[2] = (short)f2bf(v[2]);
        o[3] = (short)f2bf(v[3]);
        ((short4v*)xb)[i] = o;
    }
}

// ---------------- transpose + cast weights: W (R x C) -> WT (C x R) bf16 ----------------
__global__ __launch_bounds__(256) void transpose_cast(const float* __restrict__ W,
                                                      u16* __restrict__ WT, int R, int C) {
    __shared__ float t[32][33];
    int tx = threadIdx.x & 31, ty = threadIdx.x >> 5;
    int c0 = blockIdx.x * 32, r0 = blockIdx.y * 32;
#pragma unroll
    for (int i = 0; i < 4; i++) {
        int r = r0 + ty + i * 8;
        t[ty + i * 8][tx] = W[(size_t)r * C + c0 + tx];
    }
    __syncthreads();
#pragma unroll
    for (int i = 0; i < 4; i++) {
        int c = c0 + ty + i * 8;
        WT[(size_t)c * R + r0 + tx] = f2bf(t[tx][ty + i * 8]);
    }
}

// ---------------- GEMM: C(MxN) = A(MxK,bf16) * BT(NxK,bf16)^T, fp32 out ----------------
__global__ __launch_bounds__(256) void gemm_bf16_f32(const u16* __restrict__ A,
                                                     const u16* __restrict__ BT,
                                                     float* __restrict__ C,
                                                     int M, int N, int K) {
    __shared__ u16 a_lds[128][40];  // pad 32->40 (16B-aligned rows, conflict-free)
    __shared__ u16 b_lds[128][40];
    int tid = threadIdx.x;
    int wave = tid >> 6, lane = tid & 63, quad = lane >> 4, l16 = lane & 15;
    int wm = (wave >> 1) * 64, wn = (wave & 1) * 64;
    floatx4 acc[4][4];
#pragma unroll
    for (int i = 0; i < 4; i++)
#pragma unroll
        for (int j = 0; j < 4; j++) acc[i][j] = (floatx4){0.f, 0.f, 0.f, 0.f};
    const u16* Ab = A + (size_t)(blockIdx.y * 128) * K;
    const u16* Bb = BT + (size_t)(blockIdx.x * 128) * K;
    int sr = tid >> 2;          // 0..63
    int sc = (tid & 3) * 8;     // 0,8,16,24
    for (int k0 = 0; k0 < K; k0 += 32) {
        if (k0) __syncthreads();
#pragma unroll
        for (int i = 0; i < 2; i++) {
            int row = sr + i * 64;
            *(short8*)&a_lds[row][sc] = *(const short8*)&Ab[(size_t)row * K + k0 + sc];
            *(short8*)&b_lds[row][sc] = *(const short8*)&Bb[(size_t)row * K + k0 + sc];
        }
        __syncthreads();
        short8 af[4], bfr[4];
#pragma unroll
        for (int mt = 0; mt < 4; mt++) af[mt] = *(const short8*)&a_lds[wm + mt * 16 + l16][quad * 8];
#pragma unroll
        for (int nt = 0; nt < 4; nt++) bfr[nt] = *(const short8*)&b_lds[wn + nt * 16 + l16][quad * 8];
#pragma unroll
        for (int mt = 0; mt < 4; mt++)
#pragma unroll
            for (int nt = 0; nt < 4; nt++)
                acc[mt][nt] = __builtin_amdgcn_mfma_f32_16x16x32_bf16(af[mt], bfr[nt], acc[mt][nt], 0, 0, 0);
    }
#pragma unroll
    for (int mt = 0; mt < 4; mt++)
#pragma unroll
        for (int nt = 0; nt < 4; nt++)
#pragma unroll
            for (int r = 0; r < 4; r++) {
                int row = blockIdx.y * 128 + wm + mt * 16 + quad * 4 + r;
                int col = blockIdx.x * 128 + wn + nt * 16 + l16;
                C[(size_t)row * N + col] = acc[mt][nt][r];
            }
}

// ---------------- RoPE + scatter to head-major; V transposed ----------------
__global__ __launch_bounds__(256) void rope_scatter(const float* __restrict__ QKV,
                                                    u16* __restrict__ Qb,
                                                    u16* __restrict__ Kb,
                                                    u16* __restrict__ Vt) {
    int row = blockIdx.x;  // b*L + l
    int b = row >> 11;
    int l = row & 2047;
    const float* src = QKV + (size_t)row * 1536;
    int t = threadIdx.x;
    const float LOG1E4_32 = 0.28782313662425572f;  // ln(10000)/32
    // Q: 512 rotation pairs
    for (int p = t; p < 512; p += 256) {
        int hh = p >> 5, i = p & 31;
        float x1 = src[hh * 64 + i], x2 = src[hh * 64 + i + 32];
        float invf = expf(-(float)i * LOG1E4_32);
        float fr = (float)l * invf;
        float s, c;
        sincosf(fr, &s, &c);
        size_t base = (((size_t)b * HN + hh) * LN + l) * HDN;
        Qb[base + i] = f2bf(x1 * c - x2 * s);
        Qb[base + i + 32] = f2bf(x2 * c + x1 * s);
    }
    // K: 128 rotation pairs
    if (t < 128) {
        int kv = t >> 5, i = t & 31;
        float x1 = src[1024 + kv * 64 + i], x2 = src[1024 + kv * 64 + i + 32];
        float invf = expf(-(float)i * LOG1E4_32);
        float fr = (float)l * invf;
        float s, c;
        sincosf(fr, &s, &c);
        size_t base = (((size_t)b * KVN + kv) * LN + l) * HDN;
        Kb[base + i] = f2bf(x1 * c - x2 * s);
        Kb[base + i + 32] = f2bf(x2 * c + x1 * s);
    }
    // V: 256 elems, store transposed (b, kv, d, l)
    {
        int kv = t >> 6, d = t & 63;
        float v = src[1280 + kv * 64 + d];
        Vt[(((size_t)b * KVN + kv) * HDN + d) * LN + l] = f2bf(v);
    }
}

// ---------------- Flash attention with ALiBi (non-causal) ----------------
__global__ __launch_bounds__(256) void attention_kernel(const u16* __restrict__ Qb,
                                                        const u16* __restrict__ Kb,
                                                        const u16* __restrict__ Vt,
                                                        u16* __restrict__ AO) {
    __shared__ u16 k_lds[64][72];      // [key][dim], pad 64->72
    __shared__ u16 v_lds[64][72];      // [dim][key]
    __shared__ u16 p_lds[4][16][72];   // per-wave P buffer [qrow][key]
    int qb = blockIdx.x, h = blockIdx.y, b = blockIdx.z;
    int kv = h >> 2;  // GROUPS = 4
    int tid = threadIdx.x, wave = tid >> 6, lane = tid & 63, quad = lane >> 4, l16 = lane & 15;
    int q0 = qb * 64 + wave * 16;
    const u16* Qrow = Qb + (((size_t)b * HN + h) * LN + q0 + l16) * HDN;
    short8 aq0 = *(const short8*)&Qrow[quad * 8];
    short8 aq1 = *(const short8*)&Qrow[32 + quad * 8];
    float slope = exp2f(-0.5f * (float)(h + 1));
    float mrun[4] = {-1e30f, -1e30f, -1e30f, -1e30f};
    float lrun[4] = {0.f, 0.f, 0.f, 0.f};
    floatx4 O[4];
#pragma unroll
    for (int nt = 0; nt < 4; nt++) O[nt] = (floatx4){0.f, 0.f, 0.f, 0.f};
    const u16* Kbase = Kb + (((size_t)b * KVN + kv) * LN) * HDN;
    const u16* Vbase = Vt + (((size_t)b * KVN + kv) * HDN) * LN;
    int sr = tid >> 2;       // 0..63
    int sc0 = (tid & 3) * 8;
    for (int kb = 0; kb < LN; kb += 64) {
        __syncthreads();
#pragma unroll
        for (int i = 0; i < 2; i++) {
            int c = sc0 + i * 32;
            *(short8*)&k_lds[sr][c] = *(const short8*)&Kbase[(size_t)(kb + sr) * HDN + c];
            *(short8*)&v_lds[sr][c] = *(const short8*)&Vbase[(size_t)sr * LN + kb + c];
        }
        __syncthreads();
        floatx4 S[4];
#pragma unroll
        for (int nt = 0; nt < 4; nt++) {
            floatx4 sa = (floatx4){0.f, 0.f, 0.f, 0.f};
            short8 bk0 = *(const short8*)&k_lds[nt * 16 + l16][quad * 8];
            short8 bk1 = *(const short8*)&k_lds[nt * 16 + l16][32 + quad * 8];
            sa = __builtin_amdgcn_mfma_f32_16x16x32_bf16(aq0, bk0, sa, 0, 0, 0);
            sa = __builtin_amdgcn_mfma_f32_16x16x32_bf16(aq1, bk1, sa, 0, 0, 0);
            S[nt] = sa;
        }
        float pvv[4][4];
#pragma unroll
        for (int r = 0; r < 4; r++) {
            int qg = q0 + quad * 4 + r;
            float sv[4];
#pragma unroll
            for (int nt = 0; nt < 4; nt++) {
                int kg = kb + nt * 16 + l16;
                sv[nt] = S[nt][r] * 0.125f + slope * (float)(kg - qg);
            }
            float m = fmaxf(fmaxf(sv[0], sv[1]), fmaxf(sv[2], sv[3]));
#pragma unroll
            for (int off = 1; off < 16; off <<= 1) m = fmaxf(m, __shfl_xor(m, off, 16));
            float mn = fmaxf(mrun[r], m);
            float al = __expf(mrun[r] - mn);
            mrun[r] = mn;
            float ssum = 0.f;
#pragma unroll
            for (int nt = 0; nt < 4; nt++) {
                float p = __expf(sv[nt] - mn);
                pvv[nt][r] = p;
                ssum += p;
            }
#pragma unroll
            for (int off = 1; off < 16; off <<= 1) ssum += __shfl_xor(ssum, off, 16);
            lrun[r] = lrun[r] * al + ssum;
#pragma unroll
            for (int nt = 0; nt < 4; nt++) O[nt][r] *= al;
        }
#pragma unroll
        for (int nt = 0; nt < 4; nt++)
#pragma unroll
            for (int r = 0; r < 4; r++)
                p_lds[wave][quad * 4 + r][nt * 16 + l16] = f2bf(pvv[nt][r]);
        __syncthreads();
        short8 ap0 = *(const short8*)&p_lds[wave][l16][quad * 8];
        short8 ap1 = *(const short8*)&p_lds[wave][l16][32 + quad * 8];
#pragma unroll
        for (int nt = 0; nt < 4; nt++) {
            short8 bv0 = *(const short8*)&v_lds[nt * 16 + l16][quad * 8];
            short8 bv1 = *(const short8*)&v_lds[nt * 16 + l16][32 + quad * 8];
            O[nt] = __builtin_amdgcn_mfma_f32_16x16x32_bf16(ap0, bv0, O[nt], 0, 0, 0);
            O[nt] = __builtin_amdgcn_mfma_f32_16x16x32_bf16(ap1, bv1, O[nt], 0, 0, 0);
        }
    }
#pragma unroll
    for (int r = 0; r < 4; r++) {
        float inv = 1.0f / lrun[r];
        int qg = q0 + quad * 4 + r;
        size_t base = ((size_t)b * LN + qg) * 1024 + h * 64;
#pragma unroll
        for (int nt = 0; nt < 4; nt++) AO[base + nt * 16 + l16] = f2bf(O[nt][r] * inv);
    }
}

extern "C" void kernel_launch(void* const* d_in, const int* in_sizes, int n_in,
                              void* d_out, int out_size, void* d_ws, size_t ws_size,
                              hipStream_t stream) {
    const float* x = (const float*)d_in[0];
    const float* Wq = (const float*)d_in[1];
    const float* Wk = (const float*)d_in[2];
    const float* Wv = (const float*)d_in[3];
    const float* Wo = (const float*)d_in[4];
    float* out = (float*)d_out;
    char* ws = (char*)d_ws;
    // workspace layout (bytes):
    //   xb   @ 0         : 8 MB  (bf16 x; reused as AO after GEMM1)
    //   WT   @ 8388608   : 3 MB  (WqT|WkT|WvT stacked, 1536 x 1024)
    //   WoT  @ 11534336  : 2 MB
    //   QKV  @ 13631488  : 25.2 MB (fp32 raw projections)
    //   Qb   @ 38797312  : 8 MB
    //   Kb   @ 47185920  : 2 MB
    //   Vt   @ 49283072  : 2 MB   -> total 51380224 B
    u16* xb = (u16*)(ws);
    u16* WT = (u16*)(ws + 8388608);
    u16* WoT = (u16*)(ws + 11534336);
    float* QKV = (float*)(ws + 13631488);
    u16* Qb = (u16*)(ws + 38797312);
    u16* Kb = (u16*)(ws + 47185920);
    u16* Vt = (u16*)(ws + 49283072);
    u16* AO = xb;  // alias: xb dead after GEMM1

    cast_x_kernel<<<4096, 256, 0, stream>>>(x, xb, (BN_ * LN * DN) / 4);
    transpose_cast<<<dim3(1024 / 32, 1024 / 32), 256, 0, stream>>>(Wq, WT, 1024, 1024);
    transpose_cast<<<dim3(256 / 32, 1024 / 32), 256, 0, stream>>>(Wk, WT + 1024 * 1024, 1024, 256);
    transpose_cast<<<dim3(256 / 32, 1024 / 32), 256, 0, stream>>>(Wv, WT + 1280 * 1024, 1024, 256);
    transpose_cast<<<dim3(1024 / 32, 1024 / 32), 256, 0, stream>>>(Wo, WoT, 1024, 1024);
    gemm_bf16_f32<<<dim3(1536 / 128, 4096 / 128), 256, 0, stream>>>(xb, WT, QKV, 4096, 1536, 1024);
    rope_scatter<<<4096, 256, 0, stream>>>(QKV, Qb, Kb, Vt);
    attention_kernel<<<dim3(LN / 64, HN, BN_), 256, 0, stream>>>(Qb, Kb, Vt, AO);
    gemm_bf16_f32<<<dim3(1024 / 128, 4096 / 128), 256, 0, stream>>>(AO, WoT, out, 4096, 1024, 1024);
}

// Round 2
// 224.263 us; speedup vs baseline: 1.2274x; 1.2274x over previous
//
#include <hip/hip_runtime.h>
#include <math.h>

typedef unsigned short u16;
typedef unsigned int u32;
typedef __attribute__((ext_vector_type(8))) short short8;
typedef __attribute__((ext_vector_type(4))) short short4v;
typedef __attribute__((ext_vector_type(4))) float floatx4;
typedef __attribute__((ext_vector_type(2))) unsigned int uint2v;

#define HN 16
#define KVN 4
#define HDN 64
#define BN_ 2
#define LN 2048
#define DN 1024

__device__ __forceinline__ u16 f2bf(float f) {
    u32 u = __float_as_uint(f);
    u32 r = (u + 0x7fffu + ((u >> 16) & 1u)) >> 16;
    return (u16)r;
}

// RNE-round two fp32 to bf16 and pack into one u32 (low = f0, high = f1)
__device__ __forceinline__ u32 pack2bf(float f0, float f1) {
    u32 u0 = __float_as_uint(f0);
    u32 u1 = __float_as_uint(f1);
    u0 += 0x7fffu + ((u0 >> 16) & 1u);
    u1 += 0x7fffu + ((u1 >> 16) & 1u);
    // v_perm_b32: bytes {u1,u0} -> take u0.b2,u0.b3,u1.b2,u1.b3
    return __builtin_amdgcn_perm(u1, u0, 0x07060302u);
}

// ---------------- cast x -> bf16 ----------------
__global__ __launch_bounds__(256) void cast_x_kernel(const float* __restrict__ x,
                                                     u16* __restrict__ xb, int n4) {
    int i = blockIdx.x * 256 + threadIdx.x;
    if (i < n4) {
        floatx4 v = ((const floatx4*)x)[i];
        short4v o;
        o[0] = (short)f2bf(v[0]);
        o[1] = (short)f2bf(v[1]);
        o[2] = (short)f2bf(v[2]);
        o[3] = (short)f2bf(v[3]);
        ((short4v*)xb)[i] = o;
    }
}

// ---------------- transpose + cast weights: W (R x C) -> WT (C x R) bf16 ----------------
__global__ __launch_bounds__(256) void transpose_cast(const float* __restrict__ W,
                                                      u16* __restrict__ WT, int R, int C) {
    __shared__ float t[32][33];
    int tx = threadIdx.x & 31, ty = threadIdx.x >> 5;
    int c0 = blockIdx.x * 32, r0 = blockIdx.y * 32;
#pragma unroll
    for (int i = 0; i < 4; i++) {
        int r = r0 + ty + i * 8;
        t[ty + i * 8][tx] = W[(size_t)r * C + c0 + tx];
    }
    __syncthreads();
#pragma unroll
    for (int i = 0; i < 4; i++) {
        int c = c0 + ty + i * 8;
        WT[(size_t)c * R + r0 + tx] = f2bf(t[tx][ty + i * 8]);
    }
}

// ---------------- GEMM: C(MxN) = A(MxK,bf16) * BT(NxK,bf16)^T, fp32 out ----------------
__global__ __launch_bounds__(256) void gemm_bf16_f32(const u16* __restrict__ A,
                                                     const u16* __restrict__ BT,
                                                     float* __restrict__ C,
                                                     int M, int N, int K) {
    __shared__ u16 a_lds[128][40];
    __shared__ u16 b_lds[128][40];
    int tid = threadIdx.x;
    int wave = tid >> 6, lane = tid & 63, quad = lane >> 4, l16 = lane & 15;
    int wm = (wave >> 1) * 64, wn = (wave & 1) * 64;
    floatx4 acc[4][4];
#pragma unroll
    for (int i = 0; i < 4; i++)
#pragma unroll
        for (int j = 0; j < 4; j++) acc[i][j] = (floatx4){0.f, 0.f, 0.f, 0.f};
    const u16* Ab = A + (size_t)(blockIdx.y * 128) * K;
    const u16* Bb = BT + (size_t)(blockIdx.x * 128) * K;
    int sr = tid >> 2;
    int sc = (tid & 3) * 8;
    for (int k0 = 0; k0 < K; k0 += 32) {
        if (k0) __syncthreads();
#pragma unroll
        for (int i = 0; i < 2; i++) {
            int row = sr + i * 64;
            *(short8*)&a_lds[row][sc] = *(const short8*)&Ab[(size_t)row * K + k0 + sc];
            *(short8*)&b_lds[row][sc] = *(const short8*)&Bb[(size_t)row * K + k0 + sc];
        }
        __syncthreads();
        short8 af[4], bfr[4];
#pragma unroll
        for (int mt = 0; mt < 4; mt++) af[mt] = *(const short8*)&a_lds[wm + mt * 16 + l16][quad * 8];
#pragma unroll
        for (int nt = 0; nt < 4; nt++) bfr[nt] = *(const short8*)&b_lds[wn + nt * 16 + l16][quad * 8];
#pragma unroll
        for (int mt = 0; mt < 4; mt++)
#pragma unroll
            for (int nt = 0; nt < 4; nt++)
                acc[mt][nt] = __builtin_amdgcn_mfma_f32_16x16x32_bf16(af[mt], bfr[nt], acc[mt][nt], 0, 0, 0);
    }
#pragma unroll
    for (int mt = 0; mt < 4; mt++)
#pragma unroll
        for (int nt = 0; nt < 4; nt++)
#pragma unroll
            for (int r = 0; r < 4; r++) {
                int row = blockIdx.y * 128 + wm + mt * 16 + quad * 4 + r;
                int col = blockIdx.x * 128 + wn + nt * 16 + l16;
                C[(size_t)row * N + col] = acc[mt][nt][r];
            }
}

// ---------------- RoPE + scatter to head-major; V transposed ----------------
__global__ __launch_bounds__(256) void rope_scatter(const float* __restrict__ QKV,
                                                    u16* __restrict__ Qb,
                                                    u16* __restrict__ Kb,
                                                    u16* __restrict__ Vt) {
    int row = blockIdx.x;
    int b = row >> 11;
    int l = row & 2047;
    const float* src = QKV + (size_t)row * 1536;
    int t = threadIdx.x;
    const float LOG1E4_32 = 0.28782313662425572f;  // ln(10000)/32
    for (int p = t; p < 512; p += 256) {
        int hh = p >> 5, i = p & 31;
        float x1 = src[hh * 64 + i], x2 = src[hh * 64 + i + 32];
        float invf = expf(-(float)i * LOG1E4_32);
        float fr = (float)l * invf;
        float s, c;
        sincosf(fr, &s, &c);
        size_t base = (((size_t)b * HN + hh) * LN + l) * HDN;
        Qb[base + i] = f2bf(x1 * c - x2 * s);
        Qb[base + i + 32] = f2bf(x2 * c + x1 * s);
    }
    if (t < 128) {
        int kv = t >> 5, i = t & 31;
        float x1 = src[1024 + kv * 64 + i], x2 = src[1024 + kv * 64 + i + 32];
        float invf = expf(-(float)i * LOG1E4_32);
        float fr = (float)l * invf;
        float s, c;
        sincosf(fr, &s, &c);
        size_t base = (((size_t)b * KVN + kv) * LN + l) * HDN;
        Kb[base + i] = f2bf(x1 * c - x2 * s);
        Kb[base + i + 32] = f2bf(x2 * c + x1 * s);
    }
    {
        int kv = t >> 6, d = t & 63;
        float v = src[1280 + kv * 64 + d];
        Vt[(((size_t)b * KVN + kv) * HDN + d) * LN + l] = f2bf(v);
    }
}

// ---------------- Attention: fixed-max softmax, S^T / O^T formulation ----------------
// S^T = K·Q^T  (mfma A=K rows, B=Q rows)  -> lane holds col q=l16, row key=quad*4+r
// P stored [q][k] (lane's 4 values contiguous in k -> one b64 write per nt)
// O^T = Vt·P^T (mfma A=Vt rows (d), B=P rows (q)) -> lane holds q=l16, d=quad*4+r
__global__ __launch_bounds__(256) void attention_kernel(const u16* __restrict__ Qb,
                                                        const u16* __restrict__ Kb,
                                                        const u16* __restrict__ Vt,
                                                        u16* __restrict__ AO) {
    __shared__ u16 k_lds[64][72];     // [key][dim]
    __shared__ u16 v_lds[64][72];     // [dim][key]
    __shared__ u16 p_lds[4][16][72];  // per-wave, [q][key]
    int qb = blockIdx.x, h = blockIdx.y, b = blockIdx.z;
    int kv = h >> 2;
    int tid = threadIdx.x, wave = tid >> 6, lane = tid & 63, quad = lane >> 4, l16 = lane & 15;
    int q0 = qb * 64 + wave * 16;
    const u16* Qrow = Qb + (((size_t)b * HN + h) * LN + q0 + l16) * HDN;
    short8 bq0 = *(const short8*)&Qrow[quad * 8];
    short8 bq1 = *(const short8*)&Qrow[32 + quad * 8];
    const float LOG2E = 1.4426950408889634f;
    float slope = exp2f(-0.5f * (float)(h + 1));
    float sLE = slope * LOG2E;
    float c1 = 0.125f * LOG2E;
    // fixed max per row q: m = slope*(L-1-q) + 12 (qk/8 sigma ~0.4 -> huge margin, no overflow)
    // exp2 argument = S*c1 + sLE*(kg - (L-1)) - 12*LOG2E ; q-term cancels.
    float koff[4][4];
#pragma unroll
    for (int nt = 0; nt < 4; nt++)
#pragma unroll
        for (int r = 0; r < 4; r++)
            koff[nt][r] = sLE * (float)(nt * 16 + quad * 4 + r - (LN - 1)) - 12.0f * LOG2E;
    float kbrun = 0.0f;
    float kstep = 64.0f * sLE;
    float lsum = 0.0f;
    floatx4 O[4];
#pragma unroll
    for (int md = 0; md < 4; md++) O[md] = (floatx4){0.f, 0.f, 0.f, 0.f};
    const u16* Kbase = Kb + (((size_t)b * KVN + kv) * LN) * HDN;
    const u16* Vbase = Vt + (((size_t)b * KVN + kv) * HDN) * LN;
    int sr = tid >> 2;
    int sc0 = (tid & 3) * 8;
    for (int kb = 0; kb < LN; kb += 64) {
        __syncthreads();
#pragma unroll
        for (int i = 0; i < 2; i++) {
            int c = sc0 + i * 32;
            *(short8*)&k_lds[sr][c] = *(const short8*)&Kbase[(size_t)(kb + sr) * HDN + c];
            *(short8*)&v_lds[sr][c] = *(const short8*)&Vbase[(size_t)sr * LN + kb + c];
        }
        __syncthreads();
        // S^T tiles: rows = keys (4 x 16), cols = q (16)
        floatx4 S[4];
#pragma unroll
        for (int nt = 0; nt < 4; nt++) {
            floatx4 sa = (floatx4){0.f, 0.f, 0.f, 0.f};
            short8 ak0 = *(const short8*)&k_lds[nt * 16 + l16][quad * 8];
            short8 ak1 = *(const short8*)&k_lds[nt * 16 + l16][32 + quad * 8];
            sa = __builtin_amdgcn_mfma_f32_16x16x32_bf16(ak0, bq0, sa, 0, 0, 0);
            sa = __builtin_amdgcn_mfma_f32_16x16x32_bf16(ak1, bq1, sa, 0, 0, 0);
            S[nt] = sa;
        }
        // softmax weights (no online max needed), pack to bf16, write P[q][k]
#pragma unroll
        for (int nt = 0; nt < 4; nt++) {
            float p0 = __builtin_amdgcn_exp2f(S[nt][0] * c1 + (koff[nt][0] + kbrun));
            float p1 = __builtin_amdgcn_exp2f(S[nt][1] * c1 + (koff[nt][1] + kbrun));
            float p2 = __builtin_amdgcn_exp2f(S[nt][2] * c1 + (koff[nt][2] + kbrun));
            float p3 = __builtin_amdgcn_exp2f(S[nt][3] * c1 + (koff[nt][3] + kbrun));
            lsum += (p0 + p1) + (p2 + p3);
            uint2v pk;
            pk[0] = pack2bf(p0, p1);
            pk[1] = pack2bf(p2, p3);
            *(uint2v*)&p_lds[wave][l16][nt * 16 + quad * 4] = pk;
        }
        kbrun += kstep;
        // same-wave LDS write->read: in-order, no barrier needed (per-wave buffer)
        short8 bp0 = *(const short8*)&p_lds[wave][l16][quad * 8];
        short8 bp1 = *(const short8*)&p_lds[wave][l16][32 + quad * 8];
#pragma unroll
        for (int md = 0; md < 4; md++) {
            short8 av0 = *(const short8*)&v_lds[md * 16 + l16][quad * 8];
            short8 av1 = *(const short8*)&v_lds[md * 16 + l16][32 + quad * 8];
            O[md] = __builtin_amdgcn_mfma_f32_16x16x32_bf16(av0, bp0, O[md], 0, 0, 0);
            O[md] = __builtin_amdgcn_mfma_f32_16x16x32_bf16(av1, bp1, O[md], 0, 0, 0);
        }
    }
    // reduce lsum across the 4 quads holding this q column
    lsum += __shfl_xor(lsum, 16, 64);
    lsum += __shfl_xor(lsum, 32, 64);
    float inv = 1.0f / lsum;
    int qg = q0 + l16;
    size_t base = ((size_t)b * LN + qg) * 1024 + h * 64 + quad * 4;
#pragma unroll
    for (int md = 0; md < 4; md++) {
        uint2v pk;
        pk[0] = pack2bf(O[md][0] * inv, O[md][1] * inv);
        pk[1] = pack2bf(O[md][2] * inv, O[md][3] * inv);
        *(uint2v*)&AO[base + md * 16] = pk;
    }
}

extern "C" void kernel_launch(void* const* d_in, const int* in_sizes, int n_in,
                              void* d_out, int out_size, void* d_ws, size_t ws_size,
                              hipStream_t stream) {
    const float* x = (const float*)d_in[0];
    const float* Wq = (const float*)d_in[1];
    const float* Wk = (const float*)d_in[2];
    const float* Wv = (const float*)d_in[3];
    const float* Wo = (const float*)d_in[4];
    float* out = (float*)d_out;
    char* ws = (char*)d_ws;
    u16* xb = (u16*)(ws);
    u16* WT = (u16*)(ws + 8388608);
    u16* WoT = (u16*)(ws + 11534336);
    float* QKV = (float*)(ws + 13631488);
    u16* Qb = (u16*)(ws + 38797312);
    u16* Kb = (u16*)(ws + 47185920);
    u16* Vt = (u16*)(ws + 49283072);
    u16* AO = xb;  // alias: xb dead after GEMM1

    cast_x_kernel<<<4096, 256, 0, stream>>>(x, xb, (BN_ * LN * DN) / 4);
    transpose_cast<<<dim3(1024 / 32, 1024 / 32), 256, 0, stream>>>(Wq, WT, 1024, 1024);
    transpose_cast<<<dim3(256 / 32, 1024 / 32), 256, 0, stream>>>(Wk, WT + 1024 * 1024, 1024, 256);
    transpose_cast<<<dim3(256 / 32, 1024 / 32), 256, 0, stream>>>(Wv, WT + 1280 * 1024, 1024, 256);
    transpose_cast<<<dim3(1024 / 32, 1024 / 32), 256, 0, stream>>>(Wo, WoT, 1024, 1024);
    gemm_bf16_f32<<<dim3(1536 / 128, 4096 / 128), 256, 0, stream>>>(xb, WT, QKV, 4096, 1536, 1024);
    rope_scatter<<<4096, 256, 0, stream>>>(QKV, Qb, Kb, Vt);
    attention_kernel<<<dim3(LN / 64, HN, BN_), 256, 0, stream>>>(Qb, Kb, Vt, AO);
    gemm_bf16_f32<<<dim3(1024 / 128, 4096 / 128), 256, 0, stream>>>(AO, WoT, out, 4096, 1024, 1024);
}

// Round 3
// 201.537 us; speedup vs baseline: 1.3658x; 1.1128x over previous
//
#include <hip/hip_runtime.h>
#include <math.h>

typedef unsigned short u16;
typedef unsigned int u32;
typedef __attribute__((ext_vector_type(8))) short short8;
typedef __attribute__((ext_vector_type(4))) short short4v;
typedef __attribute__((ext_vector_type(4))) float floatx4;
typedef __attribute__((ext_vector_type(2))) unsigned int uint2v;

#define HN 16
#define KVN 4
#define HDN 64
#define BN_ 2
#define LN 2048
#define DN 1024

__device__ __forceinline__ u16 f2bf(float f) {
    u32 u = __float_as_uint(f);
    u32 r = (u + 0x7fffu + ((u >> 16) & 1u)) >> 16;
    return (u16)r;
}

__device__ __forceinline__ u32 pack2bf(float f0, float f1) {
    u32 u0 = __float_as_uint(f0);
    u32 u1 = __float_as_uint(f1);
    u0 += 0x7fffu + ((u0 >> 16) & 1u);
    u1 += 0x7fffu + ((u1 >> 16) & 1u);
    return __builtin_amdgcn_perm(u1, u0, 0x07060302u);
}

// async global->LDS, 16B per lane. LDS dest must be wave-uniform base + lane*16.
__device__ __forceinline__ void gl16(const u16* g, u16* l) {
    __builtin_amdgcn_global_load_lds(
        (const __attribute__((address_space(1))) u32*)g,
        (__attribute__((address_space(3))) u32*)l, 16, 0, 0);
}

// ---------------- cast x -> bf16 ----------------
__global__ __launch_bounds__(256) void cast_x_kernel(const float* __restrict__ x,
                                                     u16* __restrict__ xb, int n4) {
    int i = blockIdx.x * 256 + threadIdx.x;
    if (i < n4) {
        floatx4 v = ((const floatx4*)x)[i];
        short4v o;
        o[0] = (short)f2bf(v[0]);
        o[1] = (short)f2bf(v[1]);
        o[2] = (short)f2bf(v[2]);
        o[3] = (short)f2bf(v[3]);
        ((short4v*)xb)[i] = o;
    }
}

// ---------------- transpose + cast weights ----------------
__global__ __launch_bounds__(256) void transpose_cast(const float* __restrict__ W,
                                                      u16* __restrict__ WT, int R, int C) {
    __shared__ float t[32][33];
    int tx = threadIdx.x & 31, ty = threadIdx.x >> 5;
    int c0 = blockIdx.x * 32, r0 = blockIdx.y * 32;
#pragma unroll
    for (int i = 0; i < 4; i++) {
        int r = r0 + ty + i * 8;
        t[ty + i * 8][tx] = W[(size_t)r * C + c0 + tx];
    }
    __syncthreads();
#pragma unroll
    for (int i = 0; i < 4; i++) {
        int c = c0 + ty + i * 8;
        WT[(size_t)c * R + r0 + tx] = f2bf(t[tx][ty + i * 8]);
    }
}

// ---------------- GEMM: C(MxN) = A(MxK,bf16) * BT(NxK,bf16)^T, fp32 out ----------------
// 128M x 64N tile, BK=32, double-buffered global_load_lds, 1 barrier/iter.
__global__ __launch_bounds__(256) void gemm_bf16_f32(const u16* __restrict__ A,
                                                     const u16* __restrict__ BT,
                                                     float* __restrict__ C,
                                                     int M, int N, int K) {
    // per buf (u16 units): aL [128][32] @0 (4096), bL [64][32] @4096 (2048) -> 6144
    __shared__ u16 sm[12288];
    int tid = threadIdx.x;
    int w = tid >> 6, l = tid & 63, quad = l >> 4, l16 = l & 15;
    int wm = (w >> 1) * 64, wn = (w & 1) * 32;
    floatx4 acc[4][2];
#pragma unroll
    for (int i = 0; i < 4; i++)
#pragma unroll
        for (int j = 0; j < 2; j++) acc[i][j] = (floatx4){0.f, 0.f, 0.f, 0.f};
    const u16* ag0 = A + (size_t)(blockIdx.y * 128 + 16 * w + (l >> 2)) * K + (l & 3) * 8;
    const u16* ag1 = ag0 + (size_t)64 * K;
    const u16* bg = BT + (size_t)(blockIdx.x * 64 + 16 * w + (l >> 2)) * K + (l & 3) * 8;
    int lbase = w * 512 + l * 8;  // u16 units, = lane*16B within wave segment
    // prologue: stage buf0
    gl16(ag0, &sm[lbase]);
    gl16(ag1, &sm[2048 + lbase]);
    gl16(bg, &sm[4096 + lbase]);
    int nit = K >> 5;
    for (int it = 0; it < nit; it++) {
        __syncthreads();  // drains last iter's loads + release prev buf
        int cur = it & 1;
        if (it + 1 < nit) {
            int nb = (cur ^ 1) * 6144;
            ag0 += 32; ag1 += 32; bg += 32;
            gl16(ag0, &sm[nb + lbase]);
            gl16(ag1, &sm[nb + 2048 + lbase]);
            gl16(bg, &sm[nb + 4096 + lbase]);
        }
        const u16* smc = &sm[cur * 6144];
        short8 af[4], bfr[2];
#pragma unroll
        for (int mt = 0; mt < 4; mt++) af[mt] = *(const short8*)&smc[(wm + mt * 16 + l16) * 32 + quad * 8];
#pragma unroll
        for (int nt = 0; nt < 2; nt++) bfr[nt] = *(const short8*)&smc[4096 + (wn + nt * 16 + l16) * 32 + quad * 8];
#pragma unroll
        for (int mt = 0; mt < 4; mt++)
#pragma unroll
            for (int nt = 0; nt < 2; nt++)
                acc[mt][nt] = __builtin_amdgcn_mfma_f32_16x16x32_bf16(af[mt], bfr[nt], acc[mt][nt], 0, 0, 0);
    }
#pragma unroll
    for (int mt = 0; mt < 4; mt++)
#pragma unroll
        for (int nt = 0; nt < 2; nt++)
#pragma unroll
            for (int r = 0; r < 4; r++) {
                int row = blockIdx.y * 128 + wm + mt * 16 + quad * 4 + r;
                int col = blockIdx.x * 64 + wn + nt * 16 + l16;
                C[(size_t)row * N + col] = acc[mt][nt][r];
            }
}

// ---------------- RoPE + scatter to head-major; V transposed ----------------
__global__ __launch_bounds__(256) void rope_scatter(const float* __restrict__ QKV,
                                                    u16* __restrict__ Qb,
                                                    u16* __restrict__ Kb,
                                                    u16* __restrict__ Vt) {
    int row = blockIdx.x;
    int b = row >> 11;
    int l = row & 2047;
    const float* src = QKV + (size_t)row * 1536;
    int t = threadIdx.x;
    const float LOG1E4_32 = 0.28782313662425572f;  // ln(10000)/32
    for (int p = t; p < 512; p += 256) {
        int hh = p >> 5, i = p & 31;
        float x1 = src[hh * 64 + i], x2 = src[hh * 64 + i + 32];
        float invf = expf(-(float)i * LOG1E4_32);
        float fr = (float)l * invf;
        float s, c;
        sincosf(fr, &s, &c);
        size_t base = (((size_t)b * HN + hh) * LN + l) * HDN;
        Qb[base + i] = f2bf(x1 * c - x2 * s);
        Qb[base + i + 32] = f2bf(x2 * c + x1 * s);
    }
    if (t < 128) {
        int kv = t >> 5, i = t & 31;
        float x1 = src[1024 + kv * 64 + i], x2 = src[1024 + kv * 64 + i + 32];
        float invf = expf(-(float)i * LOG1E4_32);
        float fr = (float)l * invf;
        float s, c;
        sincosf(fr, &s, &c);
        size_t base = (((size_t)b * KVN + kv) * LN + l) * HDN;
        Kb[base + i] = f2bf(x1 * c - x2 * s);
        Kb[base + i + 32] = f2bf(x2 * c + x1 * s);
    }
    {
        int kv = t >> 6, d = t & 63;
        float v = src[1280 + kv * 64 + d];
        Vt[(((size_t)b * KVN + kv) * HDN + d) * LN + l] = f2bf(v);
    }
}

// ---------------- Attention: fixed-max softmax, S^T/O^T, dbuf async staging ----------------
// Block: 128 q (4 waves x 2 q-tiles of 16). K/V tiles of 64 keys, dbuf, 1 barrier/iter.
// LDS (u16 units): kbuf[2] @ {0,4096}: [half d][64 key][32 d]; vbuf[2] @ {8192,12288}:
// [half k][64 d][32 k]; p @ 16384 + wave*1152: [16 q][72 k pad].
__global__ __launch_bounds__(256) void attention_kernel(const u16* __restrict__ Qb,
                                                        const u16* __restrict__ Kb,
                                                        const u16* __restrict__ Vt,
                                                        u16* __restrict__ AO) {
    __shared__ u16 sm[20992];
    int qb = blockIdx.x, h = blockIdx.y, b = blockIdx.z;
    int kv = h >> 2;
    int tid = threadIdx.x, w = tid >> 6, l = tid & 63, quad = l >> 4, l16 = l & 15;
    const u16* Kbase = Kb + (((size_t)b * KVN + kv) * LN) * HDN;
    const u16* Vbase = Vt + (((size_t)b * KVN + kv) * HDN) * LN;
    // Q fragments for 2 tiles (B-operand, rows = q)
    short8 bq[2][2];
#pragma unroll
    for (int t = 0; t < 2; t++) {
        const u16* Qrow = Qb + (((size_t)b * HN + h) * LN + qb * 128 + t * 64 + w * 16 + l16) * HDN;
        bq[t][0] = *(const short8*)&Qrow[quad * 8];
        bq[t][1] = *(const short8*)&Qrow[32 + quad * 8];
    }
    const float LOG2E = 1.4426950408889634f;
    float slope = exp2f(-0.5f * (float)(h + 1));
    float sLE = slope * LOG2E;
    float c1 = 0.125f * LOG2E;
    float koff[4][4];
#pragma unroll
    for (int nt = 0; nt < 4; nt++)
#pragma unroll
        for (int r = 0; r < 4; r++)
            koff[nt][r] = sLE * (float)(nt * 16 + quad * 4 + r - (LN - 1)) - 12.0f * LOG2E;
    float kbrun = 0.0f;
    float kstep = 64.0f * sLE;
    floatx4 O[2][4], lacc[2];
#pragma unroll
    for (int t = 0; t < 2; t++) {
        lacc[t] = (floatx4){0.f, 0.f, 0.f, 0.f};
#pragma unroll
        for (int md = 0; md < 4; md++) O[t][md] = (floatx4){0.f, 0.f, 0.f, 0.f};
    }
    short8 ones;
#pragma unroll
    for (int i = 0; i < 8; i++) ones[i] = (short)0x3F80;  // bf16 1.0
    u16* pb = &sm[16384 + w * 1152];
    int lbase = w * 512 + l * 8;  // lane*16B within wave segment
    // staging pointers (advance per iter: K +64 keys*64d, V +64 keys)
    const u16* kg = Kbase + (size_t)(16 * w + (l >> 2)) * 64 + (l & 3) * 8;
    const u16* vg = Vbase + (size_t)(16 * w + (l >> 2)) * 2048 + (l & 3) * 8;
    // prologue: stage buf0 (kb=0)
    gl16(kg, &sm[lbase]);
    gl16(kg + 32, &sm[2048 + lbase]);
    gl16(vg, &sm[8192 + lbase]);
    gl16(vg + 32, &sm[8192 + 2048 + lbase]);
    for (int it = 0; it < 32; it++) {
        __syncthreads();  // release prev buf + drain loads issued last iter
        int cur = it & 1;
        if (it + 1 < 32) {
            int nb = (cur ^ 1) * 4096;
            kg += 4096;  // next 64 keys * 64 dims
            vg += 64;    // next 64 keys
            gl16(kg, &sm[nb + lbase]);
            gl16(kg + 32, &sm[nb + 2048 + lbase]);
            gl16(vg, &sm[8192 + nb + lbase]);
            gl16(vg + 32, &sm[8192 + nb + 2048 + lbase]);
        }
        const u16* kc = &sm[cur * 4096];
        const u16* vc = &sm[8192 + cur * 4096];
        short8 ak0[4], ak1[4], av0[4], av1[4];
#pragma unroll
        for (int nt = 0; nt < 4; nt++) {
            ak0[nt] = *(const short8*)&kc[(nt * 16 + l16) * 32 + quad * 8];
            ak1[nt] = *(const short8*)&kc[2048 + (nt * 16 + l16) * 32 + quad * 8];
        }
#pragma unroll
        for (int md = 0; md < 4; md++) {
            av0[md] = *(const short8*)&vc[(md * 16 + l16) * 32 + quad * 8];
            av1[md] = *(const short8*)&vc[2048 + (md * 16 + l16) * 32 + quad * 8];
        }
        float koff2[4][4];
#pragma unroll
        for (int nt = 0; nt < 4; nt++)
#pragma unroll
            for (int r = 0; r < 4; r++) koff2[nt][r] = koff[nt][r] + kbrun;
        kbrun += kstep;
#pragma unroll
        for (int t = 0; t < 2; t++) {
            // S^T tiles
            floatx4 S[4];
#pragma unroll
            for (int nt = 0; nt < 4; nt++) {
                floatx4 sa = (floatx4){0.f, 0.f, 0.f, 0.f};
                sa = __builtin_amdgcn_mfma_f32_16x16x32_bf16(ak0[nt], bq[t][0], sa, 0, 0, 0);
                sa = __builtin_amdgcn_mfma_f32_16x16x32_bf16(ak1[nt], bq[t][1], sa, 0, 0, 0);
                S[nt] = sa;
            }
#pragma unroll
            for (int nt = 0; nt < 4; nt++) {
                float p0 = __builtin_amdgcn_exp2f(S[nt][0] * c1 + koff2[nt][0]);
                float p1 = __builtin_amdgcn_exp2f(S[nt][1] * c1 + koff2[nt][1]);
                float p2 = __builtin_amdgcn_exp2f(S[nt][2] * c1 + koff2[nt][2]);
                float p3 = __builtin_amdgcn_exp2f(S[nt][3] * c1 + koff2[nt][3]);
                uint2v pk;
                pk[0] = pack2bf(p0, p1);
                pk[1] = pack2bf(p2, p3);
                *(uint2v*)&pb[l16 * 72 + nt * 16 + quad * 4] = pk;
            }
            // same-wave LDS write->read, in order
            short8 bp0 = *(const short8*)&pb[l16 * 72 + quad * 8];
            short8 bp1 = *(const short8*)&pb[l16 * 72 + 32 + quad * 8];
#pragma unroll
            for (int md = 0; md < 4; md++) {
                O[t][md] = __builtin_amdgcn_mfma_f32_16x16x32_bf16(av0[md], bp0, O[t][md], 0, 0, 0);
                O[t][md] = __builtin_amdgcn_mfma_f32_16x16x32_bf16(av1[md], bp1, O[t][md], 0, 0, 0);
            }
            lacc[t] = __builtin_amdgcn_mfma_f32_16x16x32_bf16(ones, bp0, lacc[t], 0, 0, 0);
            lacc[t] = __builtin_amdgcn_mfma_f32_16x16x32_bf16(ones, bp1, lacc[t], 0, 0, 0);
        }
    }
#pragma unroll
    for (int t = 0; t < 2; t++) {
        float inv = 1.0f / lacc[t][0];  // all 4 rows equal = sum_k P[q]
        int qg = qb * 128 + t * 64 + w * 16 + l16;
        size_t base = ((size_t)b * LN + qg) * 1024 + h * 64 + quad * 4;
#pragma unroll
        for (int md = 0; md < 4; md++) {
            uint2v pk;
            pk[0] = pack2bf(O[t][md][0] * inv, O[t][md][1] * inv);
            pk[1] = pack2bf(O[t][md][2] * inv, O[t][md][3] * inv);
            *(uint2v*)&AO[base + md * 16] = pk;
        }
    }
}

extern "C" void kernel_launch(void* const* d_in, const int* in_sizes, int n_in,
                              void* d_out, int out_size, void* d_ws, size_t ws_size,
                              hipStream_t stream) {
    const float* x = (const float*)d_in[0];
    const float* Wq = (const float*)d_in[1];
    const float* Wk = (const float*)d_in[2];
    const float* Wv = (const float*)d_in[3];
    const float* Wo = (const float*)d_in[4];
    float* out = (float*)d_out;
    char* ws = (char*)d_ws;
    u16* xb = (u16*)(ws);
    u16* WT = (u16*)(ws + 8388608);
    u16* WoT = (u16*)(ws + 11534336);
    float* QKV = (float*)(ws + 13631488);
    u16* Qb = (u16*)(ws + 38797312);
    u16* Kb = (u16*)(ws + 47185920);
    u16* Vt = (u16*)(ws + 49283072);
    u16* AO = xb;  // alias: xb dead after GEMM1

    cast_x_kernel<<<4096, 256, 0, stream>>>(x, xb, (BN_ * LN * DN) / 4);
    transpose_cast<<<dim3(1024 / 32, 1024 / 32), 256, 0, stream>>>(Wq, WT, 1024, 1024);
    transpose_cast<<<dim3(256 / 32, 1024 / 32), 256, 0, stream>>>(Wk, WT + 1024 * 1024, 1024, 256);
    transpose_cast<<<dim3(256 / 32, 1024 / 32), 256, 0, stream>>>(Wv, WT + 1280 * 1024, 1024, 256);
    transpose_cast<<<dim3(1024 / 32, 1024 / 32), 256, 0, stream>>>(Wo, WoT, 1024, 1024);
    gemm_bf16_f32<<<dim3(1536 / 64, 4096 / 128), 256, 0, stream>>>(xb, WT, QKV, 4096, 1536, 1024);
    rope_scatter<<<4096, 256, 0, stream>>>(QKV, Qb, Kb, Vt);
    attention_kernel<<<dim3(LN / 128, HN, BN_), 256, 0, stream>>>(Qb, Kb, Vt, AO);
    gemm_bf16_f32<<<dim3(1024 / 64, 4096 / 128), 256, 0, stream>>>(AO, WoT, out, 4096, 1024, 1024);
}